// Round 3
// baseline (4004.762 us; speedup 1.0000x reference)
//
#include <hip/hip_runtime.h>
#include <cmath>

#define BB 16
#define TT 2048
#define II 512
#define HH 512
#define NSL 4            // WGs (H-slices) per batch
#define RS  128          // rows per slice
#define SCAN_THREADS 512

// ---------------------------------------------------------------------------
// GEMM (NT): C[m][n] = act( sum_k A[m][k]*B[n][k] + bias[n] )
// A: MxK row-major, B: NxK row-major, C: MxN row-major.
// Tiles BM=BN=128, BK=16; 256 threads; 8x8 micro-tile per thread.
// ACT: 0 = identity, 1 = tanh
// ---------------------------------------------------------------------------
template<int ACT>
__global__ __launch_bounds__(256) void gemm_nt(const float* __restrict__ A,
                                               const float* __restrict__ B,
                                               const float* __restrict__ bias,
                                               float* __restrict__ C,
                                               int M, int N, int K)
{
    __shared__ float As[16][132];   // [k][m], padded
    __shared__ float Bs[16][132];   // [k][n], padded

    const int m0  = blockIdx.x * 128;
    const int n0  = blockIdx.y * 128;
    const int tid = threadIdx.x;
    const int tm  = tid & 15;    // row group (8 rows)
    const int tn  = tid >> 4;    // col group (8 cols)

    float acc[8][8];
#pragma unroll
    for (int i = 0; i < 8; ++i)
#pragma unroll
        for (int jj = 0; jj < 8; ++jj) acc[i][jj] = 0.f;

    const int lr = tid >> 1;          // 0..127 row within tile
    const int lh = (tid & 1) * 8;     // k offset 0 or 8

    for (int k0 = 0; k0 < K; k0 += 16) {
        // global -> regs
        const float4* ap = (const float4*)&A[(size_t)(m0 + lr) * K + k0 + lh];
        float4 a0 = ap[0], a1 = ap[1];
        const float4* bp = (const float4*)&B[(size_t)(n0 + lr) * K + k0 + lh];
        float4 b0 = bp[0], b1 = bp[1];

        __syncthreads();   // previous iteration's LDS reads complete
        // transpose-store to LDS: As[k][m]
        As[lh + 0][lr] = a0.x; As[lh + 1][lr] = a0.y; As[lh + 2][lr] = a0.z; As[lh + 3][lr] = a0.w;
        As[lh + 4][lr] = a1.x; As[lh + 5][lr] = a1.y; As[lh + 6][lr] = a1.z; As[lh + 7][lr] = a1.w;
        Bs[lh + 0][lr] = b0.x; Bs[lh + 1][lr] = b0.y; Bs[lh + 2][lr] = b0.z; Bs[lh + 3][lr] = b0.w;
        Bs[lh + 4][lr] = b1.x; Bs[lh + 5][lr] = b1.y; Bs[lh + 6][lr] = b1.z; Bs[lh + 7][lr] = b1.w;
        __syncthreads();

#pragma unroll
        for (int kk = 0; kk < 16; ++kk) {
            float4 av0 = *(const float4*)&As[kk][tm * 8];
            float4 av1 = *(const float4*)&As[kk][tm * 8 + 4];
            float4 bv0 = *(const float4*)&Bs[kk][tn * 8];
            float4 bv1 = *(const float4*)&Bs[kk][tn * 8 + 4];
            const float ar[8] = {av0.x, av0.y, av0.z, av0.w, av1.x, av1.y, av1.z, av1.w};
            const float br[8] = {bv0.x, bv0.y, bv0.z, bv0.w, bv1.x, bv1.y, bv1.z, bv1.w};
#pragma unroll
            for (int i = 0; i < 8; ++i)
#pragma unroll
                for (int jj = 0; jj < 8; ++jj)
                    acc[i][jj] = fmaf(ar[i], br[jj], acc[i][jj]);
        }
    }

    // epilogue
    float bias_r[8];
#pragma unroll
    for (int jj = 0; jj < 8; ++jj) bias_r[jj] = bias[n0 + tn * 8 + jj];

#pragma unroll
    for (int i = 0; i < 8; ++i) {
        const int m = m0 + tm * 8 + i;
        float o[8];
#pragma unroll
        for (int jj = 0; jj < 8; ++jj) {
            float v = acc[i][jj] + bias_r[jj];
            o[jj] = (ACT == 1) ? tanhf(v) : v;
        }
        float4* cp = (float4*)&C[(size_t)m * N + n0 + tn * 8];
        cp[0] = make_float4(o[0], o[1], o[2], o[3]);
        cp[1] = make_float4(o[4], o[5], o[6], o[7]);
    }
}

// ---------------------------------------------------------------------------
// Sequential scan. Grid = 64 WGs = 16 batches x 4 H-slices (128 rows each).
// W_rec slice is REGISTER-resident: 512 threads x 128 VGPRs (fp32), loaded
// once (launch_bounds(512,2) caps VGPRs at 256 so it cannot spill).
//
// Cross-WG handshake: each h element is a u64 = (tag << 32) | fp32_bits,
// written with ONE relaxed agent-scope atomic store (per-XCD L2s are not
// cross-coherent, so device-coherent ops are required). Consumers spin
// directly on the element they need until tag == t. Data and flag share a
// word, so no fences/counters — critical path is ~1 coherence round trip
// instead of 3 (store->counter->spin->load). Double-buffered by parity;
// safe because a producer can only overwrite h_{t-1} after all WGs consumed
// it (it must first have consumed all of h_t, which transitively requires
// every WG to have finished step t-1).
// The WG's own slice short-circuits through persistent LDS (hown).
// All 64 WGs are co-resident (<= 256 CUs), so spinning cannot deadlock.
// ---------------------------------------------------------------------------
__global__ __launch_bounds__(SCAN_THREADS, 2) void scan_kernel(
    const float* __restrict__ W_rec,
    const float* __restrict__ a_all,
    float* __restrict__ zout,                    // d_out: z_all in, h_t out
    unsigned long long* __restrict__ htag)       // [2][BB][HH] tagged h
{
    __shared__ float hs[HH];
    __shared__ float zs[RS];
    __shared__ float as_[RS];
    __shared__ float part[NSL][RS];      // [k-partition][row]
    __shared__ float hown[RS];           // own slice carried across steps

    const int tid = threadIdx.x;
    const int b   = blockIdx.x >> 2;     // batch
    const int s   = blockIdx.x & 3;      // slice
    const int j0  = s * RS;
    const int j   = tid & (RS - 1);      // output row within slice
    const int p   = tid >> 7;            // 0..3 k-partition (128 k each)
    const bool own = (tid >= j0) && (tid < j0 + RS);

    // Register-resident W slice: this thread owns row (j0+j), k in [p*128, +128)
    float w[128];
    {
        const float4* src = (const float4*)&W_rec[(size_t)(j0 + j) * HH + p * 128];
#pragma unroll
        for (int i = 0; i < 32; ++i) {
            float4 v = src[i];
            w[4 * i + 0] = v.x; w[4 * i + 1] = v.y;
            w[4 * i + 2] = v.z; w[4 * i + 3] = v.w;
        }
    }
    if (tid < RS) hown[tid] = 0.f;       // h_0 = 0
    // no barrier needed yet; first-iter barrier below covers hown init?  No:
    // own-range threads read hown before the first barrier -> sync here once.
    __syncthreads();

    const size_t hbase = (size_t)b * HH;

    for (int t = 0; t < TT; ++t) {
        const size_t rowoff = ((size_t)b * TT + t) * HH + j0;
        // independent global loads first: overlap with the h-poll below
        float zv = 0.f, av = 0.f;
        if (tid < RS) {
            zv = zout[rowoff + tid];     // written by gemm1; kernel-boundary coherent
            av = a_all[rowoff + tid];
        }

        // gather h_{t-1}
        if (own) {
            hs[tid] = hown[tid - j0];
        } else {
            const unsigned long long* hp =
                &htag[(size_t)(t & 1) * BB * HH + hbase + tid];
            const unsigned int want = (unsigned int)t;
            unsigned long long v = __hip_atomic_load(hp, __ATOMIC_RELAXED,
                                                     __HIP_MEMORY_SCOPE_AGENT);
            while ((unsigned int)(v >> 32) != want) {
                __builtin_amdgcn_s_sleep(1);
                v = __hip_atomic_load(hp, __ATOMIC_RELAXED,
                                      __HIP_MEMORY_SCOPE_AGENT);
            }
            hs[tid] = __uint_as_float((unsigned int)v);
        }
        if (tid < RS) { zs[tid] = zv; as_[tid] = av; }
        __syncthreads();

        // partial dot: h[p*128 .. +128) . w  (uniform-broadcast LDS reads, reg W)
        float acc = 0.f;
        {
            const float4* hv4 = (const float4*)&hs[p * 128];
#pragma unroll
            for (int i = 0; i < 32; ++i) {
                float4 hv = hv4[i];
                acc = fmaf(w[4 * i + 0], hv.x, acc);
                acc = fmaf(w[4 * i + 1], hv.y, acc);
                acc = fmaf(w[4 * i + 2], hv.z, acc);
                acc = fmaf(w[4 * i + 3], hv.w, acc);
            }
        }
        part[p][j] = acc;
        __syncthreads();

        if (tid < RS) {
            float v  = part[0][tid] + part[1][tid] + part[2][tid] + part[3][tid]
                     + as_[tid];
            float u  = 1.f / (1.f + expf(-v));
            float hp = hs[j0 + tid];
            float z  = zs[tid];
            float hn = fmaf(u, hp - z, z);   // u*h + (1-u)*z
            hown[tid] = hn;
            unsigned long long pack =
                ((unsigned long long)(unsigned int)(t + 1) << 32) |
                (unsigned long long)__float_as_uint(hn);
            __hip_atomic_store(&htag[(size_t)((t + 1) & 1) * BB * HH + hbase + j0 + tid],
                               pack, __ATOMIC_RELAXED, __HIP_MEMORY_SCOPE_AGENT);
            zout[rowoff + tid] = hn;         // final output; read after kernel end
        }
        __syncthreads();   // hown/part/hs safe for next iteration
    }
}

// ---------------------------------------------------------------------------
extern "C" void kernel_launch(void* const* d_in, const int* in_sizes, int n_in,
                              void* d_out, int out_size, void* d_ws, size_t ws_size,
                              hipStream_t stream)
{
    const float* X     = (const float*)d_in[0];  // [16][2048][512]
    const float* W_in  = (const float*)d_in[1];  // [512][512]
    const float* b_in  = (const float*)d_in[2];  // [512]
    const float* W_rec = (const float*)d_in[3];  // [512][512]
    const float* U_z   = (const float*)d_in[4];  // [512][512]
    const float* b_u   = (const float*)d_in[5];  // [512]
    float* out = (float*)d_out;

    float* a_all = (float*)d_ws;                                         // 64 MB
    unsigned long long* htag =
        (unsigned long long*)((char*)d_ws + (size_t)BB * TT * HH * 4);   // 128 KB

    // zero the tagged h buffer (ws is re-poisoned to 0xAA before every call;
    // tag 0 + bits 0.0f encodes h_0 = 0)
    hipMemsetAsync(htag, 0, (size_t)2 * BB * HH * 8, stream);

    dim3 blk(256);
    dim3 g1(BB * TT / 128, HH / 128);
    // z_all = tanh(X @ W_in^T + b_in) -> staged in d_out
    gemm_nt<1><<<g1, blk, 0, stream>>>(X, W_in, b_in, out, BB * TT, HH, II);
    // a_all = z_all @ U_z^T + b_u -> ws
    gemm_nt<0><<<g1, blk, 0, stream>>>(out, U_z, b_u, a_all, BB * TT, HH, HH);
    // sequential gated scan (overwrites d_out with h_t)
    scan_kernel<<<dim3(BB * NSL), dim3(SCAN_THREADS), 0, stream>>>(W_rec, a_all, out, htag);
}